// Round 4
// baseline (166.953 us; speedup 1.0000x reference)
//
#include <hip/hip_runtime.h>
#include <stdint.h>

// out[m,n] = prod_d softplus(min(Zm,Ze)-max(zm,ze)) / softplus(Zm-zm)
//
// R4 structure: two kernels.
//  1) ivr_pre: materializes into d_ws, already tiled+transposed:
//       EeT[tile][phase][d:32][n:64] = e^{Ze},  IeT same = e^{-ze}
//       EmT[mtile][phase][d:32][m:32] = e^{Zm}, ImT same = e^{-zm}
//       RcG[mtile][chunk:8][m:32] = 1/prod_{8 d's} log2(1+e^{Zm-zm})
//     (~20 MB traffic; amortizes the exp/transpose work that R2/R3 redid
//      per block: entity exps were recomputed 8x, men exps 157x.)
//  2) ivr_main: staging is PURE global_load_lds 16B DMA (no VALU, no
//     transpose-write bank conflicts; LDS layout == lane order, stride 64/32
//     so main-loop reads are ds_read_b128/b64 with only free 2-way aliasing).
//     LDS = 25 KB -> 6 blocks/CU. Main loop per pair: min,min,fma,v_log,mul
//     (v_log issue rate is the floor).
// Math (unchanged from R2/R3, absmax 5.6e-17): product-of-ratios in log2
// domain (ln2^64 cancels num/denom); e^{hi-lo} = min(e^Zm,e^Ze)*min(e^-zm,e^-ze);
// per-8-d-chunk denominator reciprocal (chunk prod >= ~1e-30, finite).
//
// Fallback: if ws_size < ~10.4 MB, launch the self-contained R2 kernel.

#define BM 32
#define BN 64
#define DH 32

__device__ __forceinline__ void dma16(const float* g, float* l) {
    __builtin_amdgcn_global_load_lds(
        (const __attribute__((address_space(1))) void*)g,
        (__attribute__((address_space(3))) void*)l, 16, 0, 0);
}

// ---------------- pre-kernel: exp/transpose factory ----------------
__global__ __launch_bounds__(256)
void ivr_pre(const float* __restrict__ men, const float* __restrict__ en,
             float* __restrict__ ws, int M, int N, int ntl) {
    float* EeT = ws;                                 // [ntl][2][32][64]
    float* IeT = EeT + (size_t)ntl * 4096;
    float* EmT = IeT + (size_t)ntl * 4096;           // [8][2][32][32]
    float* ImT = EmT + 16384;
    float* RcG = ImT + 16384;                        // [8][8][32]
    const int b = blockIdx.x, tx = threadIdx.x;
    if (b < ntl) {
        const int n0 = b * BN;
        #pragma unroll
        for (int i = 0; i < 8; ++i) {
            const int q = i * 256 + tx;              // 2048 float4-quads = 64n x 128d
            const int n = q >> 5, c4 = q & 31;
            int nn = n0 + n; if (nn >= N) nn = N - 1;
            const float4 v = *reinterpret_cast<const float4*>(en + (size_t)nn * 128 + c4 * 4);
            const float vv[4] = {v.x, v.y, v.z, v.w};
            #pragma unroll
            for (int e = 0; e < 4; ++e) {
                const int d = c4 * 4 + e;
                if (d < 64) {                        // z part -> e^{-z}
                    IeT[(size_t)b * 4096 + (d >> 5) * 2048 + (d & 31) * 64 + n] = __expf(-vv[e]);
                } else {                             // Z part -> e^{Z}
                    const int dd = d - 64;
                    EeT[(size_t)b * 4096 + (dd >> 5) * 2048 + (dd & 31) * 64 + n] = __expf(vv[e]);
                }
            }
        }
    } else {
        int m = tx; if (m >= M) m = M - 1;           // M=256: exact
        const int mt = m >> 5, ml = m & 31;
        const float* row = men + (size_t)m * 128;
        float prod[8];
        #pragma unroll
        for (int c = 0; c < 8; ++c) prod[c] = 1.0f;
        #pragma unroll
        for (int c4 = 0; c4 < 16; ++c4) {
            const float4 zv = *reinterpret_cast<const float4*>(row + c4 * 4);
            const float4 Zv = *reinterpret_cast<const float4*>(row + 64 + c4 * 4);
            const float zz[4] = {zv.x, zv.y, zv.z, zv.w};
            const float ZZ[4] = {Zv.x, Zv.y, Zv.z, Zv.w};
            #pragma unroll
            for (int e = 0; e < 4; ++e) {
                const int d = c4 * 4 + e;
                const float Em = __expf(ZZ[e]);
                const float Im = __expf(-zz[e]);
                const int idx = (mt * 2 + (d >> 5)) * 1024 + (d & 31) * 32 + ml;
                EmT[idx] = Em;
                ImT[idx] = Im;
                prod[d >> 3] *= __log2f(fmaf(Em, Im, 1.0f));
            }
        }
        #pragma unroll
        for (int c = 0; c < 8; ++c)
            RcG[mt * 256 + c * 32 + ml] = 1.0f / prod[c];
    }
}

// ---------------- main kernel: DMA staging + log-product loop ----------------
__global__ __launch_bounds__(256, 6)
void ivr_main(const float* __restrict__ ws, float* __restrict__ out,
              int M, int N, int ntl, int jst) {
    __shared__ __align__(16) float sEe[DH][BN];      // 8 KB, stride 64
    __shared__ __align__(16) float sIe[DH][BN];      // 8 KB
    __shared__ __align__(16) float sEm[DH][BM];      // 4 KB, stride 32
    __shared__ __align__(16) float sIm[DH][BM];      // 4 KB
    __shared__ __align__(16) float sRc[8][BM];       // 1 KB  -> total 25 KB

    const float* EeT = ws;
    const float* IeT = EeT + (size_t)ntl * 4096;
    const float* EmT = IeT + (size_t)ntl * 4096;
    const float* ImT = EmT + 16384;
    const float* RcG = ImT + 16384;

    const int tx = threadIdx.x;
    const int w = tx >> 6, lane = tx & 63;
    const int mt = blockIdx.y, j = blockIdx.x;
    const int ntiles = (j + jst < ntl) ? 2 : 1;
    const int ni = (tx & 15) * 4;                    // 16 n-groups of 4
    const int mi = (tx >> 4) * 2;                    // 16 m-groups of 2

    // denominator reciprocals: one 1 KB DMA by wave 0, persistent all block
    if (w == 0) dma16(RcG + mt * 256 + lane * 4, &sRc[0][0]);

    float p[2][2][4];
    #pragma unroll
    for (int t = 0; t < 2; ++t)
        #pragma unroll
        for (int i = 0; i < 2; ++i)
            #pragma unroll
            for (int jj = 0; jj < 4; ++jj) p[t][i][jj] = 1.0f;

    #pragma unroll 1
    for (int h = 0; h < 2; ++h) {
        {   // men DMA for this phase: 4 KB x2, 1 call/wave each
            const float* gEm = EmT + (mt * 2 + h) * 1024;
            const float* gIm = ImT + (mt * 2 + h) * 1024;
            dma16(gEm + w * 256 + lane * 4, &sEm[0][0] + w * 256);
            dma16(gIm + w * 256 + lane * 4, &sIm[0][0] + w * 256);
        }
        for (int t = 0; t < ntiles; ++t) {
            const int j2 = j + t * jst;
            // entity DMA: 8 KB x2, 2 calls/wave each
            const float* gE = EeT + (size_t)j2 * 4096 + h * 2048;
            const float* gI = IeT + (size_t)j2 * 4096 + h * 2048;
            const int o = w * 512 + lane * 4;
            dma16(gE + o,       &sEe[0][0] + w * 512);
            dma16(gE + o + 256, &sEe[0][0] + w * 512 + 256);
            dma16(gI + o,       &sIe[0][0] + w * 512);
            dma16(gI + o + 256, &sIe[0][0] + w * 512 + 256);
            __syncthreads();                         // drains DMA (vmcnt) + orders

            #pragma unroll 1
            for (int c = 0; c < 4; ++c) {
                #pragma unroll
                for (int k = 0; k < 8; ++k) {
                    const int dl = c * 8 + k;
                    const float2 Em2 = *reinterpret_cast<const float2*>(&sEm[dl][mi]);
                    const float2 Im2 = *reinterpret_cast<const float2*>(&sIm[dl][mi]);
                    const float4 Ee4 = *reinterpret_cast<const float4*>(&sEe[dl][ni]);
                    const float4 Ie4 = *reinterpret_cast<const float4*>(&sIe[dl][ni]);
                    const float EmA[2] = {Em2.x, Em2.y};
                    const float ImA[2] = {Im2.x, Im2.y};
                    const float EeA[4] = {Ee4.x, Ee4.y, Ee4.z, Ee4.w};
                    const float IeA[4] = {Ie4.x, Ie4.y, Ie4.z, Ie4.w};
                    #pragma unroll
                    for (int i = 0; i < 2; ++i) {
                        #pragma unroll
                        for (int jj = 0; jj < 4; ++jj) {
                            const float ww = fmaf(fminf(EmA[i], EeA[jj]),
                                                  fminf(ImA[i], IeA[jj]), 1.0f);
                            p[t][i][jj] *= __log2f(ww);
                        }
                    }
                }
                const float2 rc = *reinterpret_cast<const float2*>(&sRc[h * 4 + c][mi]);
                #pragma unroll
                for (int jj = 0; jj < 4; ++jj) { p[t][0][jj] *= rc.x; p[t][1][jj] *= rc.y; }
            }
            __syncthreads();                         // reads done before next overwrite
        }
    }

    // ---- stores ----
    for (int t = 0; t < ntiles; ++t) {
        const int n0 = (j + t * jst) * BN;
        #pragma unroll
        for (int i = 0; i < 2; ++i) {
            const int m = mt * BM + mi + i;
            if (m >= M) continue;
            const int n = n0 + ni;
            if (n + 4 <= N) {
                *reinterpret_cast<float4*>(&out[(size_t)m * N + n]) =
                    make_float4(p[t][i][0], p[t][i][1], p[t][i][2], p[t][i][3]);
            } else {
                #pragma unroll
                for (int jj = 0; jj < 4; ++jj)
                    if (n + jj < N) out[(size_t)m * N + n + jj] = p[t][i][jj];
            }
        }
    }
}

// ---------------- fallback (R2 kernel, self-contained) ----------------
#define FB_MST 34
#define FB_NST 68

__global__ __launch_bounds__(256, 3)
void ivr_fb(const float* __restrict__ men, const float* __restrict__ en,
            float* __restrict__ out, int M, int N) {
    __shared__ __align__(16) float sEm[64][FB_MST];
    __shared__ __align__(16) float sIm[64][FB_MST];
    __shared__ __align__(16) float sEe[64][FB_NST];
    __shared__ __align__(16) float sIe[64][FB_NST];
    __shared__ float sRc[8][FB_MST];

    const int tx = threadIdx.x;
    const int m0 = blockIdx.y * BM;
    const int n0 = blockIdx.x * BN;
    {
        const int m = tx >> 3;
        const int c = tx & 7;
        int mm = m0 + m; if (mm >= M) mm = M - 1;
        const float* row = men + (size_t)mm * 128;
        float prod = 1.0f;
        #pragma unroll
        for (int k = 0; k < 8; ++k) {
            const int d = c * 8 + k;
            const float Em = __expf(row[64 + d]);
            const float Im = __expf(-row[d]);
            sEm[d][m] = Em;
            sIm[d][m] = Im;
            prod *= __log2f(fmaf(Em, Im, 1.0f));
        }
        sRc[c][m] = 1.0f / prod;
    }
    for (int i = tx; i < BN * 64; i += 256) {
        const int d = i & 63;
        const int n = i >> 6;
        int nn = n0 + n; if (nn >= N) nn = N - 1;
        sEe[d][n] = __expf(en[(size_t)nn * 128 + 64 + d]);
        sIe[d][n] = __expf(-en[(size_t)nn * 128 + d]);
    }
    __syncthreads();

    const int ni = (tx & 15) * 4;
    const int mi = (tx >> 4) * 2;
    float p[2][4];
    #pragma unroll
    for (int i = 0; i < 2; ++i)
        #pragma unroll
        for (int jj = 0; jj < 4; ++jj) p[i][jj] = 1.0f;

    #pragma unroll 1
    for (int c = 0; c < 8; ++c) {
        #pragma unroll
        for (int k = 0; k < 8; ++k) {
            const int d = c * 8 + k;
            const float2 Em2 = *reinterpret_cast<const float2*>(&sEm[d][mi]);
            const float2 Im2 = *reinterpret_cast<const float2*>(&sIm[d][mi]);
            const float2 Ee0 = *reinterpret_cast<const float2*>(&sEe[d][ni]);
            const float2 Ee1 = *reinterpret_cast<const float2*>(&sEe[d][ni + 2]);
            const float2 Ie0 = *reinterpret_cast<const float2*>(&sIe[d][ni]);
            const float2 Ie1 = *reinterpret_cast<const float2*>(&sIe[d][ni + 2]);
            const float EmA[2] = {Em2.x, Em2.y};
            const float ImA[2] = {Im2.x, Im2.y};
            const float EeA[4] = {Ee0.x, Ee0.y, Ee1.x, Ee1.y};
            const float IeA[4] = {Ie0.x, Ie0.y, Ie1.x, Ie1.y};
            #pragma unroll
            for (int i = 0; i < 2; ++i)
                #pragma unroll
                for (int jj = 0; jj < 4; ++jj) {
                    const float ww = fmaf(fminf(EmA[i], EeA[jj]),
                                          fminf(ImA[i], IeA[jj]), 1.0f);
                    p[i][jj] *= __log2f(ww);
                }
        }
        const float2 rc = *reinterpret_cast<const float2*>(&sRc[c][mi]);
        #pragma unroll
        for (int jj = 0; jj < 4; ++jj) { p[0][jj] *= rc.x; p[1][jj] *= rc.y; }
    }
    #pragma unroll
    for (int i = 0; i < 2; ++i) {
        const int m = m0 + mi + i;
        if (m >= M) continue;
        const int n = n0 + ni;
        if (n + 4 <= N) {
            *reinterpret_cast<float4*>(&out[(size_t)m * N + n]) =
                make_float4(p[i][0], p[i][1], p[i][2], p[i][3]);
        } else {
            #pragma unroll
            for (int jj = 0; jj < 4; ++jj)
                if (n + jj < N) out[(size_t)m * N + n + jj] = p[i][jj];
        }
    }
}

extern "C" void kernel_launch(void* const* d_in, const int* in_sizes, int n_in,
                              void* d_out, int out_size, void* d_ws, size_t ws_size,
                              hipStream_t stream) {
    const float* men = (const float*)d_in[0];
    const float* en  = (const float*)d_in[1];
    float* out = (float*)d_out;
    const int M = in_sizes[0] / 128;              // 256
    const int N = in_sizes[1] / 128;              // 20000
    const int ntl = (N + BN - 1) / BN;            // 313
    const int jst = (ntl + 1) / 2;                // 157
    const size_t need = ((size_t)2 * ntl * 4096 + 2 * 16384 + 2048) * sizeof(float);
    if (ws_size >= need && (M & 31) == 0) {
        ivr_pre<<<dim3(ntl + 1), dim3(256), 0, stream>>>(men, en, (float*)d_ws, M, N, ntl);
        ivr_main<<<dim3(jst, M / BM), dim3(256), 0, stream>>>((const float*)d_ws, out, M, N, ntl, jst);
    } else {
        ivr_fb<<<dim3(ntl, (M + BM - 1) / BM), dim3(256), 0, stream>>>(men, en, out, M, N);
    }
}